// Round 2
// baseline (303.418 us; speedup 1.0000x reference)
//
#include <hip/hip_runtime.h>
#include <hip/hip_bf16.h>
#include <cstdint>
#include <cstddef>

// ---------------------------------------------------------------------------
// DebugBertLayer: reference overwrites q,k,v with 0.01 AFTER the projections,
// so ctx == 0.01 everywhere and ctx @ Wo.T + bo collapses to a per-channel
// constant c[i] = 0.01 * rowsum(Wo)[i] + bo[i].  Real work:
//   LN1(hidden + c) -> GEMM1(+exact GELU) -> GEMM2(+bias+residual) -> LN2.
// All I/O is FP32 (per reference dtype).  GEMMs run as bf16 MFMA with fp32
// accumulate (no fp32 MFMA on CDNA4); weights are down-converted per launch.
// ---------------------------------------------------------------------------

typedef __bf16 bf16;
typedef __attribute__((ext_vector_type(8))) __bf16 bf16x8;
typedef __attribute__((ext_vector_type(4))) __bf16 bf16x4;
typedef __attribute__((ext_vector_type(4))) float floatx4;

#define DM    768      // d_model
#define DF    3072     // d_ff
#define MROWS 8192     // B*S = 4*2048

// ---- async global->LDS, 16B per lane (wave-uniform LDS base + lane*16) ----
__device__ __forceinline__ void gl2lds16(const void* gp, void* lp) {
  __builtin_amdgcn_global_load_lds(
      (__attribute__((address_space(1))) void*)(void*)gp,
      (__attribute__((address_space(3))) void*)lp,
      16, 0, 0);
}

// ---------------------------------------------------------------------------
// fp32 -> bf16 bulk convert (8 elems/thread)
// ---------------------------------------------------------------------------
__global__ __launch_bounds__(256)
void f32_to_bf16_kernel(const float* __restrict__ in, bf16* __restrict__ outp, int n8) {
  int i = blockIdx.x * 256 + threadIdx.x;
  if (i < n8) {
    const float4* p = (const float4*)(in + (size_t)i * 8);
    float4 a = p[0], b = p[1];
    bf16x8 o;
    o[0] = (bf16)a.x; o[1] = (bf16)a.y; o[2] = (bf16)a.z; o[3] = (bf16)a.w;
    o[4] = (bf16)b.x; o[5] = (bf16)b.y; o[6] = (bf16)b.z; o[7] = (bf16)b.w;
    *(bf16x8*)(outp + (size_t)i * 8) = o;
  }
}

// ---------------------------------------------------------------------------
// c[i] = 0.01 * sum_j Wo[i][j] + bo[i]   (768 rows of 768, fp32)
// ---------------------------------------------------------------------------
__global__ __launch_bounds__(64)
void prep_cvec(const float* __restrict__ Wo, const float* __restrict__ bo,
               float* __restrict__ cvec) {
  int i = blockIdx.x * 64 + threadIdx.x;   // 12 blocks * 64 = 768
  const float4* r = (const float4*)(Wo + (size_t)i * DM);
  float s = 0.f;
  #pragma unroll 8
  for (int c = 0; c < DM / 4; ++c) {
    float4 v = r[c];
    s += v.x + v.y + v.z + v.w;
  }
  cvec[i] = 0.01f * s + bo[i];
}

// ---------------------------------------------------------------------------
// attn_out[row] = LN(hidden[row] + cvec)  -> bf16 out
// one wave per row; 768 floats = 192 float4 chunks; lane takes chunks
// lane, lane+64, lane+128 (exactly 3 each).
// ---------------------------------------------------------------------------
__global__ __launch_bounds__(64)
void ln1_kernel(const float* __restrict__ hid, const float* __restrict__ cvec,
                const float* __restrict__ g, const float* __restrict__ b,
                bf16* __restrict__ out) {
  int row  = blockIdx.x;
  int lane = threadIdx.x;
  const float4* hrow = (const float4*)(hid + (size_t)row * DM);
  const float4* cv4  = (const float4*)cvec;
  float x[12];
  float s = 0.f, sq = 0.f;
  #pragma unroll
  for (int t = 0; t < 3; ++t) {
    int c = lane + t * 64;
    float4 v = hrow[c];
    float4 cc = cv4[c];
    float xv0 = v.x + cc.x, xv1 = v.y + cc.y, xv2 = v.z + cc.z, xv3 = v.w + cc.w;
    x[t * 4 + 0] = xv0; x[t * 4 + 1] = xv1; x[t * 4 + 2] = xv2; x[t * 4 + 3] = xv3;
    s  += xv0 + xv1 + xv2 + xv3;
    sq += xv0 * xv0 + xv1 * xv1 + xv2 * xv2 + xv3 * xv3;
  }
  #pragma unroll
  for (int o = 32; o > 0; o >>= 1) { s += __shfl_xor(s, o); sq += __shfl_xor(sq, o); }
  float mu  = s * (1.0f / DM);
  float var = sq * (1.0f / DM) - mu * mu;
  float inv = rsqrtf(var + 1e-12f);
  const float4* g4 = (const float4*)g;
  const float4* b4 = (const float4*)b;
  #pragma unroll
  for (int t = 0; t < 3; ++t) {
    int c = lane + t * 64;
    float4 gg = g4[c], bb = b4[c];
    bf16x4 o4;
    o4[0] = (bf16)((x[t * 4 + 0] - mu) * inv * gg.x + bb.x);
    o4[1] = (bf16)((x[t * 4 + 1] - mu) * inv * gg.y + bb.y);
    o4[2] = (bf16)((x[t * 4 + 2] - mu) * inv * gg.z + bb.z);
    o4[3] = (bf16)((x[t * 4 + 3] - mu) * inv * gg.w + bb.w);
    *(bf16x4*)(out + (size_t)row * DM + c * 4) = o4;
  }
}

// ---------------------------------------------------------------------------
// out[row] = LN(pre[row])   fp32 in -> fp32 out
// ---------------------------------------------------------------------------
__global__ __launch_bounds__(64)
void ln2_kernel(const float* __restrict__ pre,
                const float* __restrict__ g, const float* __restrict__ b,
                float* __restrict__ out) {
  int row  = blockIdx.x;
  int lane = threadIdx.x;
  const float4* prow = (const float4*)(pre + (size_t)row * DM);
  float x[12];
  float s = 0.f, sq = 0.f;
  #pragma unroll
  for (int t = 0; t < 3; ++t) {
    int c = lane + t * 64;
    float4 v = prow[c];
    x[t * 4 + 0] = v.x; x[t * 4 + 1] = v.y; x[t * 4 + 2] = v.z; x[t * 4 + 3] = v.w;
    s  += v.x + v.y + v.z + v.w;
    sq += v.x * v.x + v.y * v.y + v.z * v.z + v.w * v.w;
  }
  #pragma unroll
  for (int o = 32; o > 0; o >>= 1) { s += __shfl_xor(s, o); sq += __shfl_xor(sq, o); }
  float mu  = s * (1.0f / DM);
  float var = sq * (1.0f / DM) - mu * mu;
  float inv = rsqrtf(var + 1e-12f);
  const float4* g4 = (const float4*)g;
  const float4* b4 = (const float4*)b;
  float4* orow = (float4*)(out + (size_t)row * DM);
  #pragma unroll
  for (int t = 0; t < 3; ++t) {
    int c = lane + t * 64;
    float4 gg = g4[c], bb = b4[c];
    float4 o;
    o.x = (x[t * 4 + 0] - mu) * inv * gg.x + bb.x;
    o.y = (x[t * 4 + 1] - mu) * inv * gg.y + bb.y;
    o.z = (x[t * 4 + 2] - mu) * inv * gg.z + bb.z;
    o.w = (x[t * 4 + 3] - mu) * inv * gg.w + bb.w;
    orow[c] = o;
  }
}

// ---------------------------------------------------------------------------
// NT bf16 MFMA GEMM, 128x128 tile, BK=64, 4 waves of 4x4 16x16x32 tiles.
// A: [M][K] bf16 (K-contig), B: [N][K] bf16 (K-contig).  Bias fp32.
// EPI==0: out bf16 = gelu_exact(acc + bias[n])                 (GEMM1 -> h)
// EPI==1: out fp32 = acc + bias[n] + (float)resid[m*DM + n]    (GEMM2 -> pre)
// ---------------------------------------------------------------------------
#define BM 128
#define BN 128
#define BK 64

template <int EPI>
__global__ __launch_bounds__(256)
void gemm_nt(const bf16* __restrict__ A, const bf16* __restrict__ B,
             const float* __restrict__ bias, const bf16* __restrict__ resid,
             void* __restrict__ out, int M, int N, int K) {
  __shared__ bf16 lds_a[BM * BK];   // 16 KB
  __shared__ bf16 lds_b[BN * BK];   // 16 KB

  const int tid   = threadIdx.x;
  const int wave  = tid >> 6;
  const int lane  = tid & 63;
  const int quad  = lane >> 4;
  const int row16 = lane & 15;

  const int m0 = blockIdx.y * BM;
  const int n0 = blockIdx.x * BN;
  const int wm = (wave >> 1) * 64;
  const int wn = (wave & 1) * 64;

  floatx4 acc[4][4] = {};

  const bf16* Ablk = A + (size_t)m0 * K;
  const bf16* Bblk = B + (size_t)n0 * K;

  for (int kk = 0; kk < K; kk += BK) {
    // stage 128x64 bf16 tiles of A and B: 1024 16B-chunks each, 4/thread
    #pragma unroll
    for (int i = 0; i < 4; ++i) {
      int ci = tid + 256 * i;        // 0..1023 ; LDS addr = uniform + lane*16
      int r  = ci >> 3;
      int c  = ci & 7;
      gl2lds16(Ablk + (size_t)r * K + kk + c * 8, lds_a + ci * 8);
      gl2lds16(Bblk + (size_t)r * K + kk + c * 8, lds_b + ci * 8);
    }
    __syncthreads();

    #pragma unroll
    for (int ks = 0; ks < BK; ks += 32) {
      bf16x8 af[4], bfr[4];
      #pragma unroll
      for (int i = 0; i < 4; ++i)
        af[i] = *(const bf16x8*)&lds_a[(wm + i * 16 + row16) * BK + ks + quad * 8];
      #pragma unroll
      for (int j = 0; j < 4; ++j)
        bfr[j] = *(const bf16x8*)&lds_b[(wn + j * 16 + row16) * BK + ks + quad * 8];
      #pragma unroll
      for (int i = 0; i < 4; ++i)
        #pragma unroll
        for (int j = 0; j < 4; ++j)
          acc[i][j] = __builtin_amdgcn_mfma_f32_16x16x32_bf16(af[i], bfr[j], acc[i][j], 0, 0, 0);
    }
    __syncthreads();
  }

  // epilogue: C/D layout col = lane&15, row = quad*4 + reg
  #pragma unroll
  for (int i = 0; i < 4; ++i) {
    int grow = m0 + wm + i * 16 + quad * 4;
    #pragma unroll
    for (int j = 0; j < 4; ++j) {
      int gcol = n0 + wn + j * 16 + row16;
      float bia = bias[gcol];
      #pragma unroll
      for (int r = 0; r < 4; ++r) {
        float x = acc[i][j][r] + bia;
        if constexpr (EPI == 0) {
          float gl = 0.5f * x * (1.0f + erff(x * 0.70710678118654752f));
          ((bf16*)out)[(size_t)(grow + r) * N + gcol] = (bf16)gl;
        } else {
          x += (float)resid[(size_t)(grow + r) * DM + gcol];
          ((float*)out)[(size_t)(grow + r) * N + gcol] = x;
        }
      }
    }
  }
}

// ---------------------------------------------------------------------------
extern "C" void kernel_launch(void* const* d_in, const int* in_sizes, int n_in,
                              void* d_out, int out_size, void* d_ws, size_t ws_size,
                              hipStream_t stream) {
  (void)in_sizes; (void)n_in; (void)out_size; (void)ws_size;

  const float* hidden = (const float*)d_in[0];
  const float* Wo     = (const float*)d_in[7];
  const float* bo     = (const float*)d_in[8];
  const float* ln1_g  = (const float*)d_in[9];
  const float* ln1_b  = (const float*)d_in[10];
  const float* Wi     = (const float*)d_in[11];
  const float* bi     = (const float*)d_in[12];
  const float* Wf     = (const float*)d_in[13];
  const float* bf_    = (const float*)d_in[14];
  const float* ln2_g  = (const float*)d_in[15];
  const float* ln2_b  = (const float*)d_in[16];
  float* out = (float*)d_out;

  // workspace layout (total ~93 MB)
  char* w = (char*)d_ws;
  float* cvec = (float*)w;                                  // 3 KB (pad 4 KB)
  size_t off = 4096;
  bf16* attn = (bf16*)(w + off); off += (size_t)MROWS * DM * 2;   // 12.6 MB
  bf16* h    = (bf16*)(w + off); off += (size_t)MROWS * DF * 2;   // 50.3 MB
  float* pre = (float*)(w + off); off += (size_t)MROWS * DM * 4;  // 25.2 MB
  bf16* Wib  = (bf16*)(w + off); off += (size_t)DF * DM * 2;      // 4.7 MB
  bf16* Wfb  = (bf16*)(w + off);                                  // 4.7 MB

  // 0. weight down-converts (per launch; graph-safe, same work every call)
  f32_to_bf16_kernel<<<dim3((DF * DM / 8 + 255) / 256), dim3(256), 0, stream>>>(Wi, Wib, DF * DM / 8);
  f32_to_bf16_kernel<<<dim3((DM * DF / 8 + 255) / 256), dim3(256), 0, stream>>>(Wf, Wfb, DM * DF / 8);

  // 1. constant attention-output vector
  prep_cvec<<<dim3(DM / 64), dim3(64), 0, stream>>>(Wo, bo, cvec);

  // 2. attn = LN1(hidden + cvec)  (bf16)
  ln1_kernel<<<dim3(MROWS), dim3(64), 0, stream>>>(hidden, cvec, ln1_g, ln1_b, attn);

  // 3. h = gelu(attn @ Wi^T + bi)      M=8192 N=3072 K=768
  gemm_nt<0><<<dim3(DF / BN, MROWS / BM), dim3(256), 0, stream>>>(
      attn, Wib, bi, nullptr, h, MROWS, DF, DM);

  // 4. pre = h @ Wf^T + bf + attn      M=8192 N=768 K=3072
  gemm_nt<1><<<dim3(DM / BN, MROWS / BM), dim3(256), 0, stream>>>(
      h, Wfb, bf_, attn, pre, MROWS, DM, DF);

  // 5. out = LN2(pre)
  ln2_kernel<<<dim3(MROWS), dim3(64), 0, stream>>>(pre, ln2_g, ln2_b, out);
}

// Round 3
// 269.330 us; speedup vs baseline: 1.1266x; 1.1266x over previous
//
#include <hip/hip_runtime.h>
#include <hip/hip_bf16.h>
#include <cstdint>
#include <cstddef>

// ---------------------------------------------------------------------------
// DebugBertLayer: reference overwrites q,k,v with 0.01 AFTER the projections,
// so ctx == 0.01 and ctx @ Wo.T + bo collapses to a per-channel constant
// c[i] = 0.01 * rowsum(Wo)[i] + bo[i].  Real work:
//   LN1(hidden + c) -> GEMM1(+exact GELU) -> GEMM2 (split-K=2) -> LN2(combine).
// FP32 I/O; GEMMs are bf16 MFMA w/ fp32 accumulate; weights converted/launch.
// R3 changes: XOR-swizzled LDS staging (kills 16-way bank conflicts that
// cost ~26% of GEMM time), split-K=2 for GEMM2 (384 -> 768 blocks),
// LN2 fuses the split-K combine + bias + residual.
// ---------------------------------------------------------------------------

typedef __bf16 bf16;
typedef __attribute__((ext_vector_type(8))) __bf16 bf16x8;
typedef __attribute__((ext_vector_type(4))) __bf16 bf16x4;
typedef __attribute__((ext_vector_type(4))) float floatx4;

#define DM    768      // d_model
#define DF    3072     // d_ff
#define MROWS 8192     // B*S = 4*2048

__device__ __forceinline__ void gl2lds16(const void* gp, void* lp) {
  __builtin_amdgcn_global_load_lds(
      (__attribute__((address_space(1))) void*)(void*)gp,
      (__attribute__((address_space(3))) void*)lp,
      16, 0, 0);
}

// ---------------------------------------------------------------------------
__global__ __launch_bounds__(256)
void f32_to_bf16_kernel(const float* __restrict__ in, bf16* __restrict__ outp, int n8) {
  int i = blockIdx.x * 256 + threadIdx.x;
  if (i < n8) {
    const float4* p = (const float4*)(in + (size_t)i * 8);
    float4 a = p[0], b = p[1];
    bf16x8 o;
    o[0] = (bf16)a.x; o[1] = (bf16)a.y; o[2] = (bf16)a.z; o[3] = (bf16)a.w;
    o[4] = (bf16)b.x; o[5] = (bf16)b.y; o[6] = (bf16)b.z; o[7] = (bf16)b.w;
    *(bf16x8*)(outp + (size_t)i * 8) = o;
  }
}

// ---------------------------------------------------------------------------
__global__ __launch_bounds__(64)
void prep_cvec(const float* __restrict__ Wo, const float* __restrict__ bo,
               float* __restrict__ cvec) {
  int i = blockIdx.x * 64 + threadIdx.x;   // 12 blocks * 64 = 768
  const float4* r = (const float4*)(Wo + (size_t)i * DM);
  float s = 0.f;
  #pragma unroll 8
  for (int c = 0; c < DM / 4; ++c) {
    float4 v = r[c];
    s += v.x + v.y + v.z + v.w;
  }
  cvec[i] = 0.01f * s + bo[i];
}

// ---------------------------------------------------------------------------
// attn_out[row] = LN(hidden[row] + cvec) -> bf16
// ---------------------------------------------------------------------------
__global__ __launch_bounds__(64)
void ln1_kernel(const float* __restrict__ hid, const float* __restrict__ cvec,
                const float* __restrict__ g, const float* __restrict__ b,
                bf16* __restrict__ out) {
  int row  = blockIdx.x;
  int lane = threadIdx.x;
  const float4* hrow = (const float4*)(hid + (size_t)row * DM);
  const float4* cv4  = (const float4*)cvec;
  float x[12];
  float s = 0.f, sq = 0.f;
  #pragma unroll
  for (int t = 0; t < 3; ++t) {
    int c = lane + t * 64;
    float4 v = hrow[c];
    float4 cc = cv4[c];
    float x0 = v.x + cc.x, x1 = v.y + cc.y, x2 = v.z + cc.z, x3 = v.w + cc.w;
    x[t*4+0] = x0; x[t*4+1] = x1; x[t*4+2] = x2; x[t*4+3] = x3;
    s  += x0 + x1 + x2 + x3;
    sq += x0*x0 + x1*x1 + x2*x2 + x3*x3;
  }
  #pragma unroll
  for (int o = 32; o > 0; o >>= 1) { s += __shfl_xor(s, o); sq += __shfl_xor(sq, o); }
  float mu  = s * (1.0f / DM);
  float var = sq * (1.0f / DM) - mu * mu;
  float inv = rsqrtf(var + 1e-12f);
  const float4* g4 = (const float4*)g;
  const float4* b4 = (const float4*)b;
  #pragma unroll
  for (int t = 0; t < 3; ++t) {
    int c = lane + t * 64;
    float4 gg = g4[c], bb = b4[c];
    bf16x4 o4;
    o4[0] = (bf16)((x[t*4+0] - mu) * inv * gg.x + bb.x);
    o4[1] = (bf16)((x[t*4+1] - mu) * inv * gg.y + bb.y);
    o4[2] = (bf16)((x[t*4+2] - mu) * inv * gg.z + bb.z);
    o4[3] = (bf16)((x[t*4+3] - mu) * inv * gg.w + bb.w);
    *(bf16x4*)(out + (size_t)row * DM + c * 4) = o4;
  }
}

// ---------------------------------------------------------------------------
// out[row] = LN( p0[row] + p1[row] + bias + attn[row] )   fp32 out
// (fuses split-K combine + fc2 bias + residual)
// ---------------------------------------------------------------------------
__global__ __launch_bounds__(64)
void ln2_kernel(const float* __restrict__ p0, const float* __restrict__ p1,
                const float* __restrict__ bias, const bf16* __restrict__ attn,
                const float* __restrict__ g, const float* __restrict__ b,
                float* __restrict__ out) {
  int row  = blockIdx.x;
  int lane = threadIdx.x;
  const float4* r0 = (const float4*)(p0 + (size_t)row * DM);
  const float4* r1 = (const float4*)(p1 + (size_t)row * DM);
  const float4* bi4 = (const float4*)bias;
  const bf16* arow = attn + (size_t)row * DM;
  float x[12];
  float s = 0.f, sq = 0.f;
  #pragma unroll
  for (int t = 0; t < 3; ++t) {
    int c = lane + t * 64;
    float4 a = r0[c], d = r1[c], bb = bi4[c];
    bf16x4 rv = *(const bf16x4*)(arow + c * 4);
    float x0 = a.x + d.x + bb.x + (float)rv[0];
    float x1 = a.y + d.y + bb.y + (float)rv[1];
    float x2 = a.z + d.z + bb.z + (float)rv[2];
    float x3 = a.w + d.w + bb.w + (float)rv[3];
    x[t*4+0] = x0; x[t*4+1] = x1; x[t*4+2] = x2; x[t*4+3] = x3;
    s  += x0 + x1 + x2 + x3;
    sq += x0*x0 + x1*x1 + x2*x2 + x3*x3;
  }
  #pragma unroll
  for (int o = 32; o > 0; o >>= 1) { s += __shfl_xor(s, o); sq += __shfl_xor(sq, o); }
  float mu  = s * (1.0f / DM);
  float var = sq * (1.0f / DM) - mu * mu;
  float inv = rsqrtf(var + 1e-12f);
  const float4* g4 = (const float4*)g;
  const float4* b4 = (const float4*)b;
  float4* orow = (float4*)(out + (size_t)row * DM);
  #pragma unroll
  for (int t = 0; t < 3; ++t) {
    int c = lane + t * 64;
    float4 gg = g4[c], bb = b4[c];
    float4 o;
    o.x = (x[t*4+0] - mu) * inv * gg.x + bb.x;
    o.y = (x[t*4+1] - mu) * inv * gg.y + bb.y;
    o.z = (x[t*4+2] - mu) * inv * gg.z + bb.z;
    o.w = (x[t*4+3] - mu) * inv * gg.w + bb.w;
    orow[c] = o;
  }
}

// ---------------------------------------------------------------------------
// NT bf16 MFMA GEMM, 128x128 tile, BK=64, 4 waves of 4x4 16x16x32 tiles.
// XOR-swizzled LDS staging: LDS slot (r, c) holds global chunk (r, c^(r&7)).
// Reader XORs the same -> 8 lanes per 4-bank group (conflict-free ideal).
// EPI==0: out bf16 = gelu_exact(acc + bias[n])              (GEMM1 -> h)
// EPI==1: out fp32 = acc  (split-K partial; combine in LN2) (GEMM2 -> pre[z])
// ---------------------------------------------------------------------------
#define BM 128
#define BN 128
#define BK 64

template <int EPI>
__global__ __launch_bounds__(256, 3)
void gemm_nt(const bf16* __restrict__ A, const bf16* __restrict__ B,
             const float* __restrict__ bias,
             void* __restrict__ out, int M, int N, int K, int ksplit) {
  __shared__ bf16 lds_a[BM * BK];   // 16 KB
  __shared__ bf16 lds_b[BN * BK];   // 16 KB

  const int tid   = threadIdx.x;
  const int wave  = tid >> 6;
  const int lane  = tid & 63;
  const int quad  = lane >> 4;
  const int row16 = lane & 15;
  const int xorv  = row16 & 7;       // reader-side swizzle key

  const int m0 = blockIdx.y * BM;
  const int n0 = blockIdx.x * BN;
  const int wm = (wave >> 1) * 64;
  const int wn = (wave & 1) * 64;

  const int kbeg = blockIdx.z * ksplit;
  const int kend = kbeg + ksplit;

  floatx4 acc[4][4] = {};

  const bf16* Ablk = A + (size_t)m0 * K;
  const bf16* Bblk = B + (size_t)n0 * K;

  for (int kk = kbeg; kk < kend; kk += BK) {
    // stage 128x64 tiles: 1024 16B-chunks each, 4 per thread, swizzled
    #pragma unroll
    for (int i = 0; i < 4; ++i) {
      int ci  = tid + 256 * i;          // LDS slot (lane-contiguous, forced)
      int r   = ci >> 3;
      int c_g = (ci & 7) ^ (r & 7);     // global chunk this slot holds
      gl2lds16(Ablk + (size_t)r * K + kk + c_g * 8, lds_a + ci * 8);
      gl2lds16(Bblk + (size_t)r * K + kk + c_g * 8, lds_b + ci * 8);
    }
    __syncthreads();

    #pragma unroll
    for (int ks = 0; ks < BK; ks += 32) {
      const int cs = ((ks >> 3) + quad) ^ xorv;   // swizzled chunk to read
      bf16x8 af[4], bfr[4];
      #pragma unroll
      for (int i = 0; i < 4; ++i)
        af[i] = *(const bf16x8*)&lds_a[(wm + i * 16 + row16) * BK + cs * 8];
      #pragma unroll
      for (int j = 0; j < 4; ++j)
        bfr[j] = *(const bf16x8*)&lds_b[(wn + j * 16 + row16) * BK + cs * 8];
      #pragma unroll
      for (int i = 0; i < 4; ++i)
        #pragma unroll
        for (int j = 0; j < 4; ++j)
          acc[i][j] = __builtin_amdgcn_mfma_f32_16x16x32_bf16(af[i], bfr[j], acc[i][j], 0, 0, 0);
    }
    __syncthreads();
  }

  // epilogue: C/D layout col = lane&15, row = quad*4 + reg
  #pragma unroll
  for (int i = 0; i < 4; ++i) {
    int grow = m0 + wm + i * 16 + quad * 4;
    #pragma unroll
    for (int j = 0; j < 4; ++j) {
      int gcol = n0 + wn + j * 16 + row16;
      if constexpr (EPI == 0) {
        float bia = bias[gcol];
        #pragma unroll
        for (int r = 0; r < 4; ++r) {
          float x = acc[i][j][r] + bia;
          float gl = 0.5f * x * (1.0f + erff(x * 0.70710678118654752f));
          ((bf16*)out)[(size_t)(grow + r) * N + gcol] = (bf16)gl;
        }
      } else {
        float* po = (float*)out + (size_t)blockIdx.z * M * N;
        #pragma unroll
        for (int r = 0; r < 4; ++r)
          po[(size_t)(grow + r) * N + gcol] = acc[i][j][r];
      }
    }
  }
}

// ---------------------------------------------------------------------------
extern "C" void kernel_launch(void* const* d_in, const int* in_sizes, int n_in,
                              void* d_out, int out_size, void* d_ws, size_t ws_size,
                              hipStream_t stream) {
  (void)in_sizes; (void)n_in; (void)out_size; (void)ws_size;

  const float* hidden = (const float*)d_in[0];
  const float* Wo     = (const float*)d_in[7];
  const float* bo     = (const float*)d_in[8];
  const float* ln1_g  = (const float*)d_in[9];
  const float* ln1_b  = (const float*)d_in[10];
  const float* Wi     = (const float*)d_in[11];
  const float* bi     = (const float*)d_in[12];
  const float* Wf     = (const float*)d_in[13];
  const float* bf_    = (const float*)d_in[14];
  const float* ln2_g  = (const float*)d_in[15];
  const float* ln2_b  = (const float*)d_in[16];
  float* out = (float*)d_out;

  // workspace layout (~118 MB)
  char* w = (char*)d_ws;
  float* cvec = (float*)w;
  size_t off = 4096;
  bf16* attn = (bf16*)(w + off); off += (size_t)MROWS * DM * 2;        // 12.6 MB
  bf16* h    = (bf16*)(w + off); off += (size_t)MROWS * DF * 2;        // 50.3 MB
  float* pre = (float*)(w + off); off += (size_t)2 * MROWS * DM * 4;   // 50.3 MB (2 splits)
  bf16* Wib  = (bf16*)(w + off); off += (size_t)DF * DM * 2;           // 4.7 MB
  bf16* Wfb  = (bf16*)(w + off);                                       // 4.7 MB

  // 0. weight down-converts
  f32_to_bf16_kernel<<<dim3((DF * DM / 8 + 255) / 256), dim3(256), 0, stream>>>(Wi, Wib, DF * DM / 8);
  f32_to_bf16_kernel<<<dim3((DM * DF / 8 + 255) / 256), dim3(256), 0, stream>>>(Wf, Wfb, DM * DF / 8);

  // 1. constant attention-output vector
  prep_cvec<<<dim3(DM / 64), dim3(64), 0, stream>>>(Wo, bo, cvec);

  // 2. attn = LN1(hidden + cvec)  (bf16)
  ln1_kernel<<<dim3(MROWS), dim3(64), 0, stream>>>(hidden, cvec, ln1_g, ln1_b, attn);

  // 3. h = gelu(attn @ Wi^T + bi)      M=8192 N=3072 K=768
  gemm_nt<0><<<dim3(DF / BN, MROWS / BM, 1), dim3(256), 0, stream>>>(
      attn, Wib, bi, h, MROWS, DF, DM, DM);

  // 4. pre[z] = h @ Wf^T (K-half z)    M=8192 N=768 K=3072, split-K=2
  gemm_nt<1><<<dim3(DM / BN, MROWS / BM, 2), dim3(256), 0, stream>>>(
      h, Wfb, nullptr, pre, MROWS, DM, DF, DF / 2);

  // 5. out = LN2(pre0 + pre1 + bf + attn)
  ln2_kernel<<<dim3(MROWS), dim3(64), 0, stream>>>(
      pre, pre + (size_t)MROWS * DM, bf_, attn, ln2_g, ln2_b, out);
}

// Round 4
// 264.649 us; speedup vs baseline: 1.1465x; 1.0177x over previous
//
#include <hip/hip_runtime.h>
#include <hip/hip_bf16.h>
#include <cstdint>
#include <cstddef>

// ---------------------------------------------------------------------------
// DebugBertLayer: reference overwrites q,k,v with 0.01 AFTER the projections,
// so ctx == 0.01 and ctx @ Wo.T + bo collapses to a per-channel constant
// c[i] = 0.01 * rowsum(Wo)[i] + bo[i].  Real work:
//   LN1(hidden + c) -> GEMM1(+exact GELU) -> GEMM2 (split-K=2) -> LN2(combine).
// FP32 I/O; GEMMs are bf16 MFMA w/ fp32 accumulate.
// R4: LDS-transposed coalesced epilogue (kills 64x scattered 2B stores that
// dominated the short-K tail), bf16 split-K partials, merged converts,
// 256-thread LN blocks, launch_bounds reverted to plain 256.
// ---------------------------------------------------------------------------

typedef __bf16 bf16;
typedef __attribute__((ext_vector_type(8))) __bf16 bf16x8;
typedef __attribute__((ext_vector_type(4))) __bf16 bf16x4;
typedef __attribute__((ext_vector_type(4))) float floatx4;

#define DM    768      // d_model
#define DF    3072     // d_ff
#define MROWS 8192     // B*S = 4*2048

__device__ __forceinline__ void gl2lds16(const void* gp, void* lp) {
  __builtin_amdgcn_global_load_lds(
      (__attribute__((address_space(1))) void*)(void*)gp,
      (__attribute__((address_space(3))) void*)lp,
      16, 0, 0);
}

// ---------------------------------------------------------------------------
// one dispatch converts BOTH weight matrices (same element count)
// ---------------------------------------------------------------------------
__global__ __launch_bounds__(256)
void f32_to_bf16_dual(const float* __restrict__ a, const float* __restrict__ b,
                      bf16* __restrict__ oa, bf16* __restrict__ ob, int n8) {
  int i = blockIdx.x * 256 + threadIdx.x;
  const float* src = (i < n8) ? a : b;
  bf16* dst        = (i < n8) ? oa : ob;
  int k            = (i < n8) ? i : i - n8;
  const float4* p = (const float4*)(src + (size_t)k * 8);
  float4 x = p[0], y = p[1];
  bf16x8 o;
  o[0]=(bf16)x.x; o[1]=(bf16)x.y; o[2]=(bf16)x.z; o[3]=(bf16)x.w;
  o[4]=(bf16)y.x; o[5]=(bf16)y.y; o[6]=(bf16)y.z; o[7]=(bf16)y.w;
  *(bf16x8*)(dst + (size_t)k * 8) = o;
}

// ---------------------------------------------------------------------------
__global__ __launch_bounds__(64)
void prep_cvec(const float* __restrict__ Wo, const float* __restrict__ bo,
               float* __restrict__ cvec) {
  int i = blockIdx.x * 64 + threadIdx.x;   // 12 blocks * 64 = 768
  const float4* r = (const float4*)(Wo + (size_t)i * DM);
  float s = 0.f;
  #pragma unroll 8
  for (int c = 0; c < DM / 4; ++c) {
    float4 v = r[c];
    s += v.x + v.y + v.z + v.w;
  }
  cvec[i] = 0.01f * s + bo[i];
}

// ---------------------------------------------------------------------------
// attn_out[row] = LN(hidden[row] + cvec) -> bf16.  4 rows/block (wave each).
// ---------------------------------------------------------------------------
__global__ __launch_bounds__(256)
void ln1_kernel(const float* __restrict__ hid, const float* __restrict__ cvec,
                const float* __restrict__ g, const float* __restrict__ b,
                bf16* __restrict__ out) {
  int row  = blockIdx.x * 4 + (threadIdx.x >> 6);
  int lane = threadIdx.x & 63;
  const float4* hrow = (const float4*)(hid + (size_t)row * DM);
  const float4* cv4  = (const float4*)cvec;
  float x[12];
  float s = 0.f, sq = 0.f;
  #pragma unroll
  for (int t = 0; t < 3; ++t) {
    int c = lane + t * 64;
    float4 v = hrow[c];
    float4 cc = cv4[c];
    float x0 = v.x + cc.x, x1 = v.y + cc.y, x2 = v.z + cc.z, x3 = v.w + cc.w;
    x[t*4+0] = x0; x[t*4+1] = x1; x[t*4+2] = x2; x[t*4+3] = x3;
    s  += x0 + x1 + x2 + x3;
    sq += x0*x0 + x1*x1 + x2*x2 + x3*x3;
  }
  #pragma unroll
  for (int o = 32; o > 0; o >>= 1) { s += __shfl_xor(s, o); sq += __shfl_xor(sq, o); }
  float mu  = s * (1.0f / DM);
  float var = sq * (1.0f / DM) - mu * mu;
  float inv = rsqrtf(var + 1e-12f);
  const float4* g4 = (const float4*)g;
  const float4* b4 = (const float4*)b;
  #pragma unroll
  for (int t = 0; t < 3; ++t) {
    int c = lane + t * 64;
    float4 gg = g4[c], bb = b4[c];
    bf16x4 o4;
    o4[0] = (bf16)((x[t*4+0] - mu) * inv * gg.x + bb.x);
    o4[1] = (bf16)((x[t*4+1] - mu) * inv * gg.y + bb.y);
    o4[2] = (bf16)((x[t*4+2] - mu) * inv * gg.z + bb.z);
    o4[3] = (bf16)((x[t*4+3] - mu) * inv * gg.w + bb.w);
    *(bf16x4*)(out + (size_t)row * DM + c * 4) = o4;
  }
}

// ---------------------------------------------------------------------------
// out[row] = LN( p0 + p1 + bias + attn )   (bf16 partials) -> fp32 out
// ---------------------------------------------------------------------------
__global__ __launch_bounds__(256)
void ln2_kernel(const bf16* __restrict__ p0, const bf16* __restrict__ p1,
                const float* __restrict__ bias, const bf16* __restrict__ attn,
                const float* __restrict__ g, const float* __restrict__ b,
                float* __restrict__ out) {
  int row  = blockIdx.x * 4 + (threadIdx.x >> 6);
  int lane = threadIdx.x & 63;
  const bf16* r0 = p0 + (size_t)row * DM;
  const bf16* r1 = p1 + (size_t)row * DM;
  const bf16* ar = attn + (size_t)row * DM;
  const float4* bi4 = (const float4*)bias;
  float x[12];
  float s = 0.f, sq = 0.f;
  #pragma unroll
  for (int t = 0; t < 3; ++t) {
    int c = lane + t * 64;
    bf16x4 a = *(const bf16x4*)(r0 + c * 4);
    bf16x4 d = *(const bf16x4*)(r1 + c * 4);
    bf16x4 rv = *(const bf16x4*)(ar + c * 4);
    float4 bb = bi4[c];
    float x0 = (float)a[0] + (float)d[0] + bb.x + (float)rv[0];
    float x1 = (float)a[1] + (float)d[1] + bb.y + (float)rv[1];
    float x2 = (float)a[2] + (float)d[2] + bb.z + (float)rv[2];
    float x3 = (float)a[3] + (float)d[3] + bb.w + (float)rv[3];
    x[t*4+0] = x0; x[t*4+1] = x1; x[t*4+2] = x2; x[t*4+3] = x3;
    s  += x0 + x1 + x2 + x3;
    sq += x0*x0 + x1*x1 + x2*x2 + x3*x3;
  }
  #pragma unroll
  for (int o = 32; o > 0; o >>= 1) { s += __shfl_xor(s, o); sq += __shfl_xor(sq, o); }
  float mu  = s * (1.0f / DM);
  float var = sq * (1.0f / DM) - mu * mu;
  float inv = rsqrtf(var + 1e-12f);
  const float4* g4 = (const float4*)g;
  const float4* b4 = (const float4*)b;
  float4* orow = (float4*)(out + (size_t)row * DM);
  #pragma unroll
  for (int t = 0; t < 3; ++t) {
    int c = lane + t * 64;
    float4 gg = g4[c], bb = b4[c];
    float4 o;
    o.x = (x[t*4+0] - mu) * inv * gg.x + bb.x;
    o.y = (x[t*4+1] - mu) * inv * gg.y + bb.y;
    o.z = (x[t*4+2] - mu) * inv * gg.z + bb.z;
    o.w = (x[t*4+3] - mu) * inv * gg.w + bb.w;
    orow[c] = o;
  }
}

// ---------------------------------------------------------------------------
// NT bf16 MFMA GEMM, 128x128 tile, BK=64, 4 waves of 4x4 16x16x32 tiles.
// XOR-swizzled LDS staging (conflict-free, verified R3).
// Epilogue: acc -> LDS (stride 136 bf16) -> coalesced bf16x8 stores.
// EPI==0: out = gelu_exact(acc + bias[n])   bf16        (GEMM1 -> h)
// EPI==1: out = acc (bf16 split-K partial, z-offset)    (GEMM2 -> pre[z])
// ---------------------------------------------------------------------------
#define BM 128
#define BN 128
#define BK 64
#define ES 136   // epilogue LDS row stride in bf16 (272 B, 16B-aligned)

template <int EPI>
__global__ __launch_bounds__(256)
void gemm_nt(const bf16* __restrict__ A, const bf16* __restrict__ B,
             const float* __restrict__ bias,
             bf16* __restrict__ out, int M, int N, int K, int ksplit) {
  __shared__ __align__(16) unsigned char smem[BM * ES * 2];  // 34816 B
  bf16* lds_a = (bf16*)smem;            // staging A: 16 KB
  bf16* lds_b = lds_a + BM * BK;        // staging B: 16 KB

  const int tid   = threadIdx.x;
  const int wave  = tid >> 6;
  const int lane  = tid & 63;
  const int quad  = lane >> 4;
  const int row16 = lane & 15;
  const int xorv  = row16 & 7;

  const int m0 = blockIdx.y * BM;
  const int n0 = blockIdx.x * BN;
  const int wm = (wave >> 1) * 64;
  const int wn = (wave & 1) * 64;

  const int kbeg = blockIdx.z * ksplit;
  const int kend = kbeg + ksplit;

  floatx4 acc[4][4] = {};

  const bf16* Ablk = A + (size_t)m0 * K;
  const bf16* Bblk = B + (size_t)n0 * K;

  for (int kk = kbeg; kk < kend; kk += BK) {
    #pragma unroll
    for (int i = 0; i < 4; ++i) {
      int ci  = tid + 256 * i;
      int r   = ci >> 3;
      int c_g = (ci & 7) ^ (r & 7);     // swizzled source chunk
      gl2lds16(Ablk + (size_t)r * K + kk + c_g * 8, lds_a + ci * 8);
      gl2lds16(Bblk + (size_t)r * K + kk + c_g * 8, lds_b + ci * 8);
    }
    __syncthreads();

    #pragma unroll
    for (int ks = 0; ks < BK; ks += 32) {
      const int cs = ((ks >> 3) + quad) ^ xorv;
      bf16x8 af[4], bfr[4];
      #pragma unroll
      for (int i = 0; i < 4; ++i)
        af[i] = *(const bf16x8*)&lds_a[(wm + i * 16 + row16) * BK + cs * 8];
      #pragma unroll
      for (int j = 0; j < 4; ++j)
        bfr[j] = *(const bf16x8*)&lds_b[(wn + j * 16 + row16) * BK + cs * 8];
      #pragma unroll
      for (int i = 0; i < 4; ++i)
        #pragma unroll
        for (int j = 0; j < 4; ++j)
          acc[i][j] = __builtin_amdgcn_mfma_f32_16x16x32_bf16(af[i], bfr[j], acc[i][j], 0, 0, 0);
    }
    __syncthreads();
  }

  // ---- epilogue: transpose through LDS, then coalesced stores ----
  bf16* eb = (bf16*)smem;

  float bia[4];
  if constexpr (EPI == 0) {
    #pragma unroll
    for (int j = 0; j < 4; ++j) bia[j] = bias[n0 + wn + j * 16 + row16];
  }

  #pragma unroll
  for (int i = 0; i < 4; ++i) {
    #pragma unroll
    for (int j = 0; j < 4; ++j) {
      int col = wn + j * 16 + row16;
      #pragma unroll
      for (int r = 0; r < 4; ++r) {
        int row = wm + i * 16 + quad * 4 + r;
        float x = acc[i][j][r];
        if constexpr (EPI == 0) {
          x += bia[j];
          x = 0.5f * x * (1.0f + erff(x * 0.70710678118654752f));
        }
        eb[row * ES + col] = (bf16)x;
      }
    }
  }
  __syncthreads();

  bf16* outp = out + (EPI == 1 ? (size_t)blockIdx.z * M * N : 0);
  const int rsub = tid >> 4;          // 0..15
  const int csub = (tid & 15) * 8;    // element col
  #pragma unroll
  for (int c = 0; c < 8; ++c) {
    int row = c * 16 + rsub;
    bf16x8 v = *(const bf16x8*)&eb[row * ES + csub];
    *(bf16x8*)&outp[(size_t)(m0 + row) * N + n0 + csub] = v;
  }
}

// ---------------------------------------------------------------------------
extern "C" void kernel_launch(void* const* d_in, const int* in_sizes, int n_in,
                              void* d_out, int out_size, void* d_ws, size_t ws_size,
                              hipStream_t stream) {
  (void)in_sizes; (void)n_in; (void)out_size; (void)ws_size;

  const float* hidden = (const float*)d_in[0];
  const float* Wo     = (const float*)d_in[7];
  const float* bo     = (const float*)d_in[8];
  const float* ln1_g  = (const float*)d_in[9];
  const float* ln1_b  = (const float*)d_in[10];
  const float* Wi     = (const float*)d_in[11];
  const float* bi     = (const float*)d_in[12];
  const float* Wf     = (const float*)d_in[13];
  const float* bf_    = (const float*)d_in[14];
  const float* ln2_g  = (const float*)d_in[15];
  const float* ln2_b  = (const float*)d_in[16];
  float* out = (float*)d_out;

  // workspace layout (~98 MB)
  char* w = (char*)d_ws;
  float* cvec = (float*)w;
  size_t off = 4096;
  bf16* attn = (bf16*)(w + off); off += (size_t)MROWS * DM * 2;        // 12.6 MB
  bf16* h    = (bf16*)(w + off); off += (size_t)MROWS * DF * 2;        // 50.3 MB
  bf16* pre  = (bf16*)(w + off); off += (size_t)2 * MROWS * DM * 2;    // 25.2 MB (2 splits)
  bf16* Wib  = (bf16*)(w + off); off += (size_t)DF * DM * 2;           // 4.7 MB
  bf16* Wfb  = (bf16*)(w + off);                                       // 4.7 MB

  // 0. both weight down-converts in one dispatch
  const int N8 = DF * DM / 8;
  f32_to_bf16_dual<<<dim3(2 * N8 / 256), dim3(256), 0, stream>>>(Wi, Wf, Wib, Wfb, N8);

  // 1. constant attention-output vector
  prep_cvec<<<dim3(DM / 64), dim3(64), 0, stream>>>(Wo, bo, cvec);

  // 2. attn = LN1(hidden + cvec)  (bf16)
  ln1_kernel<<<dim3(MROWS / 4), dim3(256), 0, stream>>>(hidden, cvec, ln1_g, ln1_b, attn);

  // 3. h = gelu(attn @ Wi^T + bi)      M=8192 N=3072 K=768
  gemm_nt<0><<<dim3(DF / BN, MROWS / BM, 1), dim3(256), 0, stream>>>(
      attn, Wib, bi, h, MROWS, DF, DM, DM);

  // 4. pre[z] = h @ Wf^T (K-half z)    M=8192 N=768 K=3072, split-K=2
  gemm_nt<1><<<dim3(DM / BN, MROWS / BM, 2), dim3(256), 0, stream>>>(
      h, Wfb, nullptr, pre, MROWS, DM, DF, DF / 2);

  // 5. out = LN2(pre0 + pre1 + bf + attn)
  ln2_kernel<<<dim3(MROWS / 4), dim3(256), 0, stream>>>(
      pre, pre + (size_t)MROWS * DM, bf_, attn, ln2_g, ln2_b, out);
}

// Round 5
// 238.399 us; speedup vs baseline: 1.2727x; 1.1101x over previous
//
#include <hip/hip_runtime.h>
#include <hip/hip_bf16.h>
#include <cstdint>
#include <cstddef>

// ---------------------------------------------------------------------------
// DebugBertLayer: reference overwrites q,k,v with 0.01 AFTER the projections,
// so ctx == 0.01 and ctx @ Wo.T + bo collapses to a per-channel constant
// c[i] = 0.01 * rowsum(Wo)[i] + bo[i].  Real work:
//   LN1(hidden + c) -> GEMM1(+GELU) -> GEMM2 (split-K=2) -> LN2(combine).
// FP32 I/O; GEMMs are bf16 MFMA w/ fp32 accumulate.
// R5: GELU via exp2-based tanh form (7 VALU inst vs ~25 for erff — epilogue
// VALU was out-costing all MFMA work, VALUBusy 59%), converts+cvec merged
// into one dispatch with wave-per-row cvec reduction.
// ---------------------------------------------------------------------------

typedef __bf16 bf16;
typedef __attribute__((ext_vector_type(8))) __bf16 bf16x8;
typedef __attribute__((ext_vector_type(4))) __bf16 bf16x4;
typedef __attribute__((ext_vector_type(4))) float floatx4;

#define DM    768      // d_model
#define DF    3072     // d_ff
#define MROWS 8192     // B*S = 4*2048

#define N8          (DF * DM / 8)          // 294912 : 8-elem groups per weight
#define CONV_BLOCKS (2 * N8 / 256)         // 2304 convert blocks
#define CVEC_BLOCKS (DM / 4)               // 192 blocks, wave per row

__device__ __forceinline__ void gl2lds16(const void* gp, void* lp) {
  __builtin_amdgcn_global_load_lds(
      (__attribute__((address_space(1))) void*)(void*)gp,
      (__attribute__((address_space(3))) void*)lp,
      16, 0, 0);
}

// fast GELU (tanh form): x * sigmoid(1.5958*(x + 0.044715*x^3))
// = x / (1 + exp2(c1*x + c2*x^3)), c1 = -1.5958*log2(e), c2 = c1*0.044715
__device__ __forceinline__ float gelu_fast(float x) {
  float x2 = x * x;
  float m  = x * __builtin_fmaf(-0.1029641f, x2, -2.3025851f);
  float e  = __builtin_amdgcn_exp2f(m);
  return x * __builtin_amdgcn_rcpf(1.0f + e);
}

// ---------------------------------------------------------------------------
// prep: blocks [0, CONV_BLOCKS) convert Wi/Wf fp32->bf16 (8 elem/thread);
//       blocks [CONV_BLOCKS, +CVEC_BLOCKS) compute cvec, one wave per row.
// ---------------------------------------------------------------------------
__global__ __launch_bounds__(256)
void prep_kernel(const float* __restrict__ Wi, const float* __restrict__ Wf,
                 bf16* __restrict__ Wib, bf16* __restrict__ Wfb,
                 const float* __restrict__ Wo, const float* __restrict__ bo,
                 float* __restrict__ cvec) {
  if (blockIdx.x < CONV_BLOCKS) {
    int i = blockIdx.x * 256 + threadIdx.x;
    const float* src = (i < N8) ? Wi : Wf;
    bf16* dst        = (i < N8) ? Wib : Wfb;
    int k            = (i < N8) ? i : i - N8;
    const float4* p = (const float4*)(src + (size_t)k * 8);
    float4 x = p[0], y = p[1];
    bf16x8 o;
    o[0]=(bf16)x.x; o[1]=(bf16)x.y; o[2]=(bf16)x.z; o[3]=(bf16)x.w;
    o[4]=(bf16)y.x; o[5]=(bf16)y.y; o[6]=(bf16)y.z; o[7]=(bf16)y.w;
    *(bf16x8*)(dst + (size_t)k * 8) = o;
  } else {
    int row  = (blockIdx.x - CONV_BLOCKS) * 4 + (threadIdx.x >> 6);
    int lane = threadIdx.x & 63;
    const float4* r = (const float4*)(Wo + (size_t)row * DM);
    float s = 0.f;
    #pragma unroll
    for (int t = 0; t < 3; ++t) {
      float4 v = r[lane + t * 64];
      s += v.x + v.y + v.z + v.w;
    }
    #pragma unroll
    for (int o = 32; o > 0; o >>= 1) s += __shfl_xor(s, o);
    if (lane == 0) cvec[row] = 0.01f * s + bo[row];
  }
}

// ---------------------------------------------------------------------------
// attn_out[row] = LN(hidden[row] + cvec) -> bf16.  4 rows/block (wave each).
// ---------------------------------------------------------------------------
__global__ __launch_bounds__(256)
void ln1_kernel(const float* __restrict__ hid, const float* __restrict__ cvec,
                const float* __restrict__ g, const float* __restrict__ b,
                bf16* __restrict__ out) {
  int row  = blockIdx.x * 4 + (threadIdx.x >> 6);
  int lane = threadIdx.x & 63;
  const float4* hrow = (const float4*)(hid + (size_t)row * DM);
  const float4* cv4  = (const float4*)cvec;
  float x[12];
  float s = 0.f, sq = 0.f;
  #pragma unroll
  for (int t = 0; t < 3; ++t) {
    int c = lane + t * 64;
    float4 v = hrow[c];
    float4 cc = cv4[c];
    float x0 = v.x + cc.x, x1 = v.y + cc.y, x2 = v.z + cc.z, x3 = v.w + cc.w;
    x[t*4+0] = x0; x[t*4+1] = x1; x[t*4+2] = x2; x[t*4+3] = x3;
    s  += x0 + x1 + x2 + x3;
    sq += x0*x0 + x1*x1 + x2*x2 + x3*x3;
  }
  #pragma unroll
  for (int o = 32; o > 0; o >>= 1) { s += __shfl_xor(s, o); sq += __shfl_xor(sq, o); }
  float mu  = s * (1.0f / DM);
  float var = sq * (1.0f / DM) - mu * mu;
  float inv = rsqrtf(var + 1e-12f);
  const float4* g4 = (const float4*)g;
  const float4* b4 = (const float4*)b;
  #pragma unroll
  for (int t = 0; t < 3; ++t) {
    int c = lane + t * 64;
    float4 gg = g4[c], bb = b4[c];
    bf16x4 o4;
    o4[0] = (bf16)((x[t*4+0] - mu) * inv * gg.x + bb.x);
    o4[1] = (bf16)((x[t*4+1] - mu) * inv * gg.y + bb.y);
    o4[2] = (bf16)((x[t*4+2] - mu) * inv * gg.z + bb.z);
    o4[3] = (bf16)((x[t*4+3] - mu) * inv * gg.w + bb.w);
    *(bf16x4*)(out + (size_t)row * DM + c * 4) = o4;
  }
}

// ---------------------------------------------------------------------------
// out[row] = LN( p0 + p1 + bias + attn )   (bf16 partials) -> fp32 out
// ---------------------------------------------------------------------------
__global__ __launch_bounds__(256)
void ln2_kernel(const bf16* __restrict__ p0, const bf16* __restrict__ p1,
                const float* __restrict__ bias, const bf16* __restrict__ attn,
                const float* __restrict__ g, const float* __restrict__ b,
                float* __restrict__ out) {
  int row  = blockIdx.x * 4 + (threadIdx.x >> 6);
  int lane = threadIdx.x & 63;
  const bf16* r0 = p0 + (size_t)row * DM;
  const bf16* r1 = p1 + (size_t)row * DM;
  const bf16* ar = attn + (size_t)row * DM;
  const float4* bi4 = (const float4*)bias;
  float x[12];
  float s = 0.f, sq = 0.f;
  #pragma unroll
  for (int t = 0; t < 3; ++t) {
    int c = lane + t * 64;
    bf16x4 a = *(const bf16x4*)(r0 + c * 4);
    bf16x4 d = *(const bf16x4*)(r1 + c * 4);
    bf16x4 rv = *(const bf16x4*)(ar + c * 4);
    float4 bb = bi4[c];
    float x0 = (float)a[0] + (float)d[0] + bb.x + (float)rv[0];
    float x1 = (float)a[1] + (float)d[1] + bb.y + (float)rv[1];
    float x2 = (float)a[2] + (float)d[2] + bb.z + (float)rv[2];
    float x3 = (float)a[3] + (float)d[3] + bb.w + (float)rv[3];
    x[t*4+0] = x0; x[t*4+1] = x1; x[t*4+2] = x2; x[t*4+3] = x3;
    s  += x0 + x1 + x2 + x3;
    sq += x0*x0 + x1*x1 + x2*x2 + x3*x3;
  }
  #pragma unroll
  for (int o = 32; o > 0; o >>= 1) { s += __shfl_xor(s, o); sq += __shfl_xor(sq, o); }
  float mu  = s * (1.0f / DM);
  float var = sq * (1.0f / DM) - mu * mu;
  float inv = rsqrtf(var + 1e-12f);
  const float4* g4 = (const float4*)g;
  const float4* b4 = (const float4*)b;
  float4* orow = (float4*)(out + (size_t)row * DM);
  #pragma unroll
  for (int t = 0; t < 3; ++t) {
    int c = lane + t * 64;
    float4 gg = g4[c], bb = b4[c];
    float4 o;
    o.x = (x[t*4+0] - mu) * inv * gg.x + bb.x;
    o.y = (x[t*4+1] - mu) * inv * gg.y + bb.y;
    o.z = (x[t*4+2] - mu) * inv * gg.z + bb.z;
    o.w = (x[t*4+3] - mu) * inv * gg.w + bb.w;
    orow[c] = o;
  }
}

// ---------------------------------------------------------------------------
// NT bf16 MFMA GEMM, 128x128 tile, BK=64, 4 waves of 4x4 16x16x32 tiles.
// XOR-swizzled LDS staging (conflict-free).  Coalesced LDS-transposed
// epilogue.  EPI==0: gelu_fast(acc+bias) bf16;  EPI==1: bf16 split-K partial.
// ---------------------------------------------------------------------------
#define BM 128
#define BN 128
#define BK 64
#define ES 136   // epilogue LDS row stride in bf16 (272 B, 16B-aligned)

template <int EPI>
__global__ __launch_bounds__(256)
void gemm_nt(const bf16* __restrict__ A, const bf16* __restrict__ B,
             const float* __restrict__ bias,
             bf16* __restrict__ out, int M, int N, int K, int ksplit) {
  __shared__ __align__(16) unsigned char smem[BM * ES * 2];  // 34816 B
  bf16* lds_a = (bf16*)smem;            // staging A: 16 KB
  bf16* lds_b = lds_a + BM * BK;        // staging B: 16 KB

  const int tid   = threadIdx.x;
  const int wave  = tid >> 6;
  const int lane  = tid & 63;
  const int quad  = lane >> 4;
  const int row16 = lane & 15;
  const int xorv  = row16 & 7;

  const int m0 = blockIdx.y * BM;
  const int n0 = blockIdx.x * BN;
  const int wm = (wave >> 1) * 64;
  const int wn = (wave & 1) * 64;

  const int kbeg = blockIdx.z * ksplit;
  const int kend = kbeg + ksplit;

  floatx4 acc[4][4] = {};

  const bf16* Ablk = A + (size_t)m0 * K;
  const bf16* Bblk = B + (size_t)n0 * K;

  for (int kk = kbeg; kk < kend; kk += BK) {
    #pragma unroll
    for (int i = 0; i < 4; ++i) {
      int ci  = tid + 256 * i;
      int r   = ci >> 3;
      int c_g = (ci & 7) ^ (r & 7);     // swizzled source chunk
      gl2lds16(Ablk + (size_t)r * K + kk + c_g * 8, lds_a + ci * 8);
      gl2lds16(Bblk + (size_t)r * K + kk + c_g * 8, lds_b + ci * 8);
    }
    __syncthreads();

    #pragma unroll
    for (int ks = 0; ks < BK; ks += 32) {
      const int cs = ((ks >> 3) + quad) ^ xorv;
      bf16x8 af[4], bfr[4];
      #pragma unroll
      for (int i = 0; i < 4; ++i)
        af[i] = *(const bf16x8*)&lds_a[(wm + i * 16 + row16) * BK + cs * 8];
      #pragma unroll
      for (int j = 0; j < 4; ++j)
        bfr[j] = *(const bf16x8*)&lds_b[(wn + j * 16 + row16) * BK + cs * 8];
      #pragma unroll
      for (int i = 0; i < 4; ++i)
        #pragma unroll
        for (int j = 0; j < 4; ++j)
          acc[i][j] = __builtin_amdgcn_mfma_f32_16x16x32_bf16(af[i], bfr[j], acc[i][j], 0, 0, 0);
    }
    __syncthreads();
  }

  // ---- epilogue: transpose through LDS, then coalesced stores ----
  bf16* eb = (bf16*)smem;

  float bia[4];
  if constexpr (EPI == 0) {
    #pragma unroll
    for (int j = 0; j < 4; ++j) bia[j] = bias[n0 + wn + j * 16 + row16];
  }

  #pragma unroll
  for (int i = 0; i < 4; ++i) {
    #pragma unroll
    for (int j = 0; j < 4; ++j) {
      int col = wn + j * 16 + row16;
      #pragma unroll
      for (int r = 0; r < 4; ++r) {
        int row = wm + i * 16 + quad * 4 + r;
        float x = acc[i][j][r];
        if constexpr (EPI == 0) x = gelu_fast(x + bia[j]);
        eb[row * ES + col] = (bf16)x;
      }
    }
  }
  __syncthreads();

  bf16* outp = out + (EPI == 1 ? (size_t)blockIdx.z * M * N : 0);
  const int rsub = tid >> 4;          // 0..15
  const int csub = (tid & 15) * 8;    // element col
  #pragma unroll
  for (int c = 0; c < 8; ++c) {
    int row = c * 16 + rsub;
    bf16x8 v = *(const bf16x8*)&eb[row * ES + csub];
    *(bf16x8*)&outp[(size_t)(m0 + row) * N + n0 + csub] = v;
  }
}

// ---------------------------------------------------------------------------
extern "C" void kernel_launch(void* const* d_in, const int* in_sizes, int n_in,
                              void* d_out, int out_size, void* d_ws, size_t ws_size,
                              hipStream_t stream) {
  (void)in_sizes; (void)n_in; (void)out_size; (void)ws_size;

  const float* hidden = (const float*)d_in[0];
  const float* Wo     = (const float*)d_in[7];
  const float* bo     = (const float*)d_in[8];
  const float* ln1_g  = (const float*)d_in[9];
  const float* ln1_b  = (const float*)d_in[10];
  const float* Wi     = (const float*)d_in[11];
  const float* bi     = (const float*)d_in[12];
  const float* Wf     = (const float*)d_in[13];
  const float* bf_    = (const float*)d_in[14];
  const float* ln2_g  = (const float*)d_in[15];
  const float* ln2_b  = (const float*)d_in[16];
  float* out = (float*)d_out;

  // workspace layout (~98 MB)
  char* w = (char*)d_ws;
  float* cvec = (float*)w;
  size_t off = 4096;
  bf16* attn = (bf16*)(w + off); off += (size_t)MROWS * DM * 2;        // 12.6 MB
  bf16* h    = (bf16*)(w + off); off += (size_t)MROWS * DF * 2;        // 50.3 MB
  bf16* pre  = (bf16*)(w + off); off += (size_t)2 * MROWS * DM * 2;    // 25.2 MB
  bf16* Wib  = (bf16*)(w + off); off += (size_t)DF * DM * 2;           // 4.7 MB
  bf16* Wfb  = (bf16*)(w + off);                                       // 4.7 MB

  // 0. weight converts + cvec, one dispatch
  prep_kernel<<<dim3(CONV_BLOCKS + CVEC_BLOCKS), dim3(256), 0, stream>>>(
      Wi, Wf, Wib, Wfb, Wo, bo, cvec);

  // 1. attn = LN1(hidden + cvec)  (bf16)
  ln1_kernel<<<dim3(MROWS / 4), dim3(256), 0, stream>>>(hidden, cvec, ln1_g, ln1_b, attn);

  // 2. h = gelu(attn @ Wi^T + bi)      M=8192 N=3072 K=768
  gemm_nt<0><<<dim3(DF / BN, MROWS / BM, 1), dim3(256), 0, stream>>>(
      attn, Wib, bi, h, MROWS, DF, DM, DM);

  // 3. pre[z] = h @ Wf^T (K-half z)    M=8192 N=768 K=3072, split-K=2
  gemm_nt<1><<<dim3(DM / BN, MROWS / BM, 2), dim3(256), 0, stream>>>(
      h, Wfb, nullptr, pre, MROWS, DM, DF, DF / 2);

  // 4. out = LN2(pre0 + pre1 + bf + attn)
  ln2_kernel<<<dim3(MROWS / 4), dim3(256), 0, stream>>>(
      pre, pre + (size_t)MROWS * DM, bf_, attn, ln2_g, ln2_b, out);
}